// Round 3
// baseline (133.655 us; speedup 1.0000x reference)
//
#include <hip/hip_runtime.h>
#include <stdint.h>

// z (32,384,28,28) fp32; codebook (2048,384) fp32.
// N tokens = 25088, D = 384, K = 2048. out = z_q (9633792 f32) + loss (1 f32).
#define M_TOK 25088
#define D_DIM 384
#define K_CB  2048
#define OUT_ELEMS 9633792

typedef __attribute__((ext_vector_type(8))) short short8;
typedef __attribute__((ext_vector_type(4))) float f32x4;

static __device__ __forceinline__ unsigned short f2bf(float f) {
    uint32_t u = __float_as_uint(f);
    u += 0x7FFF + ((u >> 16) & 1);   // RNE
    return (unsigned short)(u >> 16);
}
static __device__ __forceinline__ float bf2f(unsigned short h) {
    return __uint_as_float(((uint32_t)h) << 16);
}
static __device__ __forceinline__ void gl_lds16(const void* g, void* l) {
    __builtin_amdgcn_global_load_lds((const __attribute__((address_space(1))) void*)g,
                                     (__attribute__((address_space(3))) void*)l,
                                     16, 0, 0);
}

// ---------------- fused: z transpose (+ ||z||^2 partials) and codebook prep ----------------
__global__ __launch_bounds__(256) void prep_transpose_kernel(
    const float* __restrict__ z, const float* __restrict__ cb,
    unsigned short* __restrict__ zf, float* __restrict__ znp,
    unsigned short* __restrict__ cb16, float* __restrict__ cnorm) {
    __shared__ unsigned short tile[64 * 64];
    __shared__ float zred[4][64];
    int bid = blockIdx.x;
    int t = threadIdx.x;
    if (bid >= 2496) {               // codebook prep: 512 blocks x 4 rows
        int lane = t & 63, wv = t >> 6;
        int row = (bid - 2496) * 4 + wv;
        const float* src = cb + (size_t)row * D_DIM;
        unsigned short* dst = cb16 + (size_t)row * D_DIM;
        float ss = 0.f;
#pragma unroll
        for (int i = 0; i < 6; ++i) {
            float v = src[lane + i * 64];
            dst[lane + i * 64] = f2bf(v);
            ss += v * v;
        }
#pragma unroll
        for (int d = 32; d; d >>= 1) ss += __shfl_xor(ss, d);
        if (lane == 0) cnorm[row] = ss;
        return;
    }
    // transpose path: (b,c,s) fp32 -> (token,c) bf16, 64x64 LDS tiles, XOR swizzle
    int sT = bid % 13;
    int rem = bid / 13;
    int cT = rem % 6;
    int b  = rem / 6;
    int c0 = cT * 64, s0 = sT * 64;
    int ls = t & 63;
    int wv = t >> 6;
    float ss = 0.f;
#pragma unroll
    for (int p = 0; p < 16; ++p) {
        int ci = p * 4 + wv;
        int s = s0 + ls;
        float v = 0.f;
        if (s < 784) v = z[(size_t)(b * 384 + c0 + ci) * 784 + s];
        ss += v * v;
        int cx = ci ^ ((ls & 7) << 3);
        tile[ls * 64 + cx] = f2bf(v);
    }
    zred[wv][ls] = ss;
    __syncthreads();
    if (t < 64) {
        int s = s0 + t;
        if (s < 784)
            znp[cT * M_TOK + b * 784 + s] =
                (zred[0][t] + zred[1][t]) + (zred[2][t] + zred[3][t]);
    }
    int si = t >> 2, sub = t & 3;
    int s = s0 + si;
    if (s >= 784) return;
    int x = si & 7;
    int base0 = ((sub ^ (x >> 1)) << 4) | ((x & 1) << 3);
    int base1 = base0 ^ 8;
    uint4 v0 = *(const uint4*)&tile[si * 64 + base0];
    uint4 v1 = *(const uint4*)&tile[si * 64 + base1];
    size_t ro = (size_t)(b * 784 + s) * 384 + c0 + sub * 16;
    *(uint4*)(zf + ro)     = v0;
    *(uint4*)(zf + ro + 8) = v1;
}

// ---------------- distance GEMM + partial argmin: 256x256 8-wave counted-vmcnt pipeline ----------------
// grid 784 = 98 M-tiles x 8 N-chunks. BK=64, dbuf LDS 128 KB, 4 phases/K-tile,
// stage order A0,B0,B1,A1 (one half = 2 gl_lds/thread per phase), waits vmcnt(4)
// steady-state (never 0 mid-loop). Wave (wm,wn): rows {wm*64..+63, 128+wm*64..+63},
// cols {wn*32..+31, 128+wn*32..+31}. Phase (rh,ch) = 16 MFMA on one C-quadrant.

#define WAITB(n) do { asm volatile("s_waitcnt vmcnt(" n ")" ::: "memory"); \
    __builtin_amdgcn_s_barrier(); __builtin_amdgcn_sched_barrier(0); } while (0)
#define BARO do { __builtin_amdgcn_s_barrier(); __builtin_amdgcn_sched_barrier(0); } while (0)
#define PRIO1 __builtin_amdgcn_s_setprio(1)
#define PRIO0 __builtin_amdgcn_s_setprio(0)

#define STG(gbase, ldsbase) do { \
    gl_lds16((gbase) + (size_t)r0 * 768 + c0s, (ldsbase) + t16); \
    gl_lds16((gbase) + (size_t)(r0 + 64) * 768 + c0s, (ldsbase) + 8192 + t16); } while (0)

#define LDA(rh) do { const char* p_ = Ap + (rh) * 16384 + wmoff + rroff; \
    _Pragma("unroll") for (int f = 0; f < 4; ++f) { \
        a[f][0] = *(const short8*)(p_ + f * 2048 + k0); \
        a[f][1] = *(const short8*)(p_ + f * 2048 + k1); } } while (0)

#define LDB(bx, ch) do { const char* p_ = Bp + (ch) * 16384 + wnoff + rroff; \
    _Pragma("unroll") for (int g = 0; g < 2; ++g) { \
        bx[g][0] = *(const short8*)(p_ + g * 2048 + k0); \
        bx[g][1] = *(const short8*)(p_ + g * 2048 + k1); } } while (0)

#define MM(rh, ch, bx) do { \
    _Pragma("unroll") for (int f = 0; f < 4; ++f) \
    _Pragma("unroll") for (int g = 0; g < 2; ++g) { \
        acc[rh][ch][f][g] = __builtin_amdgcn_mfma_f32_16x16x32_bf16(a[f][0], bx[g][0], acc[rh][ch][f][g], 0, 0, 0); \
        acc[rh][ch][f][g] = __builtin_amdgcn_mfma_f32_16x16x32_bf16(a[f][1], bx[g][1], acc[rh][ch][f][g], 0, 0, 0); } } while (0)

__global__ __launch_bounds__(512, 2) void argmin3_kernel(
    const unsigned short* __restrict__ zf, const unsigned short* __restrict__ cb16,
    const float* __restrict__ cnorm, float2* __restrict__ partial) {
    extern __shared__ char smem[];   // 128 KB: A slots [0,64K), B slots [64K,128K)
    char* const sAr[2] = {smem, smem + 32768};
    char* const sBr[2] = {smem + 65536, smem + 98304};

    int t = threadIdx.x;
    int lane = t & 63, wave = t >> 6;
    int rr = lane & 15, qq = lane >> 4;
    int wm = wave >> 2, wn = wave & 3;   // 2M x 4N

    // bijective XCD swizzle: nwg=784, q=98 -> mtile-major chunks per XCD
    int raw = blockIdx.x;
    int lid = (raw & 7) * 98 + (raw >> 3);
    int mtile = lid >> 3;
    int nc = lid & 7;
    int ncb = nc * 256;

    const char* zfb = (const char*)zf + (size_t)mtile * 196608;   // 256*768
    const char* cbb = (const char*)cb16 + (size_t)nc * 196608;

    // staging thread geometry (512 threads, 16 B each; half = 128 rows x 128 B)
    uint32_t r0  = (uint32_t)t >> 3;                       // 0..63
    uint32_t c0s = (((uint32_t)t & 7u) * 16u) ^ ((r0 & 7u) << 4);
    uint32_t t16 = (uint32_t)t * 16u;

    // fragment read geometry
    uint32_t swz = ((uint32_t)rr & 7u) << 4;
    uint32_t k0 = ((uint32_t)qq * 16u) ^ swz;
    uint32_t k1 = (64u + (uint32_t)qq * 16u) ^ swz;
    uint32_t wmoff = (uint32_t)wm * 8192u;   // 64 rows
    uint32_t wnoff = (uint32_t)wn * 4096u;   // 32 rows
    uint32_t rroff = (uint32_t)rr * 128u;

    float cnr[2][2];
#pragma unroll
    for (int ch = 0; ch < 2; ++ch)
#pragma unroll
        for (int g = 0; g < 2; ++g)
            cnr[ch][g] = cnorm[ncb + ch * 128 + wn * 32 + g * 16 + rr];

    f32x4 acc[2][2][4][2];
#pragma unroll
    for (int i = 0; i < 2; ++i)
#pragma unroll
        for (int j = 0; j < 2; ++j)
#pragma unroll
            for (int f = 0; f < 4; ++f)
#pragma unroll
                for (int g = 0; g < 2; ++g)
                    acc[i][j][f][g] = (f32x4){0.f, 0.f, 0.f, 0.f};

    short8 a[4][2], b0[2][2], b1[2][2];

    // prologue: stage K-tile 0 into slot 0, order A0, B0, B1, A1
    STG(zfb, sAr[0]);
    STG(cbb, sBr[0]);
    STG(cbb + 98304, sBr[0] + 16384);
    STG(zfb + 98304, sAr[0] + 16384);

    for (int kt = 0; kt < 5; ++kt) {
        char* Ap = sAr[kt & 1]; char* Bp = sBr[kt & 1];
        char* An = sAr[(kt & 1) ^ 1]; char* Bn = sBr[(kt & 1) ^ 1];
        const char* zn_ = zfb + (kt + 1) * 128;
        const char* cn_ = cbb + (kt + 1) * 128;
        WAITB("4"); LDA(0); LDB(b0, 0); STG(zn_, An);           PRIO1; MM(0, 0, b0); PRIO0;
        WAITB("4"); LDB(b1, 1);          STG(cn_, Bn);           PRIO1; MM(0, 1, b1); PRIO0;
        WAITB("4"); LDA(1);              STG(cn_ + 98304, Bn + 16384); PRIO1; MM(1, 1, b1); PRIO0;
        BARO;                            STG(zn_ + 98304, An + 16384); PRIO1; MM(1, 0, b0); PRIO0;
    }
    {   // last K-tile (kt=5, slot 1), no staging; drain counts 4,2,0
        char* Ap = sAr[1]; char* Bp = sBr[1];
        WAITB("4"); LDA(0); LDB(b0, 0); PRIO1; MM(0, 0, b0); PRIO0;
        WAITB("2"); LDB(b1, 1);         PRIO1; MM(0, 1, b1); PRIO0;
        WAITB("0"); LDA(1);             PRIO1; MM(1, 1, b1); PRIO0;
        BARO;                           PRIO1; MM(1, 0, b0); PRIO0;
    }

    // ---- scoring + argmin over this block's 256 cols ----
    // C/D: col = ncb + ch*128 + wn*32 + g*16 + rr ; row = rh*128 + wm*64 + f*16 + qq*4 + j
    float2* comb = (float2*)smem;   // [256][4] — safe: slot-1 regions unread now
#pragma unroll
    for (int rh = 0; rh < 2; ++rh)
#pragma unroll
        for (int f = 0; f < 4; ++f)
#pragma unroll
            for (int j = 0; j < 4; ++j) {
                float v = 3.4e38f; int idx = 0;
#pragma unroll
                for (int ch = 0; ch < 2; ++ch)
#pragma unroll
                    for (int g = 0; g < 2; ++g) {
                        float val = cnr[ch][g] - 2.f * acc[rh][ch][f][g][j];
                        int col = ncb + ch * 128 + wn * 32 + g * 16 + rr;
                        if (val < v) { v = val; idx = col; }
                    }
#pragma unroll
                for (int d = 1; d < 16; d <<= 1) {
                    float ov = __shfl_xor(v, d);
                    int   oi = __shfl_xor(idx, d);
                    if (ov < v || (ov == v && oi < idx)) { v = ov; idx = oi; }
                }
                if (rr == 0) {
                    int row = rh * 128 + wm * 64 + f * 16 + qq * 4 + j;
                    float2 e; e.x = v; e.y = __int_as_float(idx);
                    comb[row * 4 + wn] = e;
                }
            }
    __builtin_amdgcn_s_barrier();
    if (t < 256) {
        float2 best = comb[t * 4];
        int bi = __float_as_int(best.y);
#pragma unroll
        for (int w = 1; w < 4; ++w) {
            float2 p = comb[t * 4 + w];
            int pi = __float_as_int(p.y);
            if (p.x < best.x || (p.x == best.x && pi < bi)) { best = p; bi = pi; }
        }
        partial[(size_t)nc * M_TOK + mtile * 256 + t] = best;
    }
}

// ---------------- combine + gather + loss ----------------
__global__ __launch_bounds__(256) void gather_combine_kernel(
    const float* __restrict__ cb, const float2* __restrict__ partial,
    const float* __restrict__ znp, float* __restrict__ out) {
    __shared__ unsigned short tile[56 * 392];
    __shared__ int lidx[56];
    int t = threadIdx.x;
    int bid = blockIdx.x;                 // 448 = 32 b * 14 sT
    int b = bid / 14, sT = bid % 14;
    int n0 = b * 784 + sT * 56;
    float lt = 0.f;
    if (t < 56) {
        int n = n0 + t;
        float2 best = partial[n];
        int bi = __float_as_int(best.y);
#pragma unroll
        for (int ch = 1; ch < 8; ++ch) {
            float2 p = partial[(size_t)ch * M_TOK + n];
            int pi = __float_as_int(p.y);
            if (p.x < best.x || (p.x == best.x && pi < bi)) { best = p; bi = pi; }
        }
        lidx[t] = bi;
        float zn = 0.f;
#pragma unroll
        for (int cT = 0; cT < 6; ++cT) zn += znp[cT * M_TOK + n];
        lt = best.x + zn;                 // ~ ||z_n - c_idx||^2
    }
    if (t < 64) {
#pragma unroll
        for (int d = 32; d; d >>= 1) lt += __shfl_xor(lt, d);
        if (t == 0) atomicAdd(out + OUT_ELEMS, lt * (1.25f / (float)OUT_ELEMS));
    }
    __syncthreads();
#pragma unroll
    for (int p = 0; p < 21; ++p) {
        int e = (p * 256 + t) * 4;
        int tok = e / 384;
        int c = e - tok * 384;
        int idx = lidx[tok];
        float4 v = *(const float4*)(cb + (size_t)idx * 384 + c);
        uint2 u;
        u.x = (uint32_t)f2bf(v.x) | ((uint32_t)f2bf(v.y) << 16);
        u.y = (uint32_t)f2bf(v.z) | ((uint32_t)f2bf(v.w) << 16);
        *(uint2*)&tile[tok * 392 + c] = u;
    }
    __syncthreads();
#pragma unroll
    for (int p = 0; p < 42; ++p) {
        int pp = p * 256 + t;
        int c = pp / 28;
        int j = (pp - c * 28) * 2;
        float f0 = bf2f(tile[j * 392 + c]);
        float f1 = bf2f(tile[(j + 1) * 392 + c]);
        size_t off = ((size_t)b * 384 + c) * 784 + (size_t)sT * 56 + j;
        float2 o; o.x = f0; o.y = f1;
        *(float2*)(out + off) = o;
    }
}

extern "C" void kernel_launch(void* const* d_in, const int* in_sizes, int n_in,
                              void* d_out, int out_size, void* d_ws, size_t ws_size,
                              hipStream_t stream) {
    const float* z  = (const float*)d_in[0];
    const float* cb = (const float*)d_in[1];
    float* out = (float*)d_out;
    char* ws = (char*)d_ws;

    // zf (token-major bf16 z, 19.3 MB) borrows d_out: fully consumed by
    // argmin3_kernel before gather_combine_kernel overwrites d_out.
    unsigned short* zf = (unsigned short*)d_out;

    unsigned short* cb16 = (unsigned short*)ws;            // 1,572,864 B
    float*  cnorm   = (float*)(ws + 1572864);              //     8,192 B
    float*  znp     = (float*)(ws + 1581056);              //   602,112 B
    float2* partial = (float2*)(ws + 2183168);             // 1,605,632 B

    hipMemsetAsync((void*)(out + OUT_ELEMS), 0, 4, stream);
    hipFuncSetAttribute((const void*)argmin3_kernel,
                        hipFuncAttributeMaxDynamicSharedMemorySize, 131072);
    prep_transpose_kernel<<<3008, 256, 0, stream>>>(z, cb, zf, znp, cb16, cnorm);
    argmin3_kernel<<<784, 512, 131072, stream>>>(zf, cb16, cnorm, partial);
    gather_combine_kernel<<<448, 256, 0, stream>>>(cb, partial, znp, out);
}

// Round 4
// 131.110 us; speedup vs baseline: 1.0194x; 1.0194x over previous
//
#include <hip/hip_runtime.h>
#include <stdint.h>

// z (32,384,28,28) fp32; codebook (2048,384) fp32.
// N tokens = 25088, D = 384, K = 2048. out = z_q (9633792 f32) + loss (1 f32).
#define M_TOK 25088
#define D_DIM 384
#define K_CB  2048
#define OUT_ELEMS 9633792
#define NC_CHUNKS 16

typedef __attribute__((ext_vector_type(8))) short short8;
typedef __attribute__((ext_vector_type(4))) float f32x4;

static __device__ __forceinline__ unsigned short f2bf(float f) {
    uint32_t u = __float_as_uint(f);
    u += 0x7FFF + ((u >> 16) & 1);   // RNE
    return (unsigned short)(u >> 16);
}
static __device__ __forceinline__ float bf2f(unsigned short h) {
    return __uint_as_float(((uint32_t)h) << 16);
}
static __device__ __forceinline__ void gl_lds16(const void* g, void* l) {
    __builtin_amdgcn_global_load_lds((const __attribute__((address_space(1))) void*)g,
                                     (__attribute__((address_space(3))) void*)l,
                                     16, 0, 0);
}

// ---------------- fused: z transpose (+ ||z||^2 partials) and codebook prep ----------------
__global__ __launch_bounds__(256) void prep_transpose_kernel(
    const float* __restrict__ z, const float* __restrict__ cb,
    unsigned short* __restrict__ zf, float* __restrict__ znp,
    unsigned short* __restrict__ cb16, float* __restrict__ cnorm) {
    __shared__ unsigned short tile[64 * 64];
    __shared__ float zred[4][64];
    int bid = blockIdx.x;
    int t = threadIdx.x;
    if (bid >= 2496) {               // codebook prep: 512 blocks x 4 rows
        int lane = t & 63, wv = t >> 6;
        int row = (bid - 2496) * 4 + wv;
        const float* src = cb + (size_t)row * D_DIM;
        unsigned short* dst = cb16 + (size_t)row * D_DIM;
        float ss = 0.f;
#pragma unroll
        for (int i = 0; i < 6; ++i) {
            float v = src[lane + i * 64];
            dst[lane + i * 64] = f2bf(v);
            ss += v * v;
        }
#pragma unroll
        for (int d = 32; d; d >>= 1) ss += __shfl_xor(ss, d);
        if (lane == 0) cnorm[row] = ss;
        return;
    }
    // transpose path: (b,c,s) fp32 -> (token,c) bf16, 64x64 LDS tiles, XOR swizzle
    int sT = bid % 13;
    int rem = bid / 13;
    int cT = rem % 6;
    int b  = rem / 6;
    int c0 = cT * 64, s0 = sT * 64;
    int ls = t & 63;
    int wv = t >> 6;
    float ss = 0.f;
#pragma unroll
    for (int p = 0; p < 16; ++p) {
        int ci = p * 4 + wv;
        int s = s0 + ls;
        float v = 0.f;
        if (s < 784) v = z[(size_t)(b * 384 + c0 + ci) * 784 + s];
        ss += v * v;
        int cx = ci ^ ((ls & 7) << 3);
        tile[ls * 64 + cx] = f2bf(v);
    }
    zred[wv][ls] = ss;
    __syncthreads();
    if (t < 64) {
        int s = s0 + t;
        if (s < 784)
            znp[cT * M_TOK + b * 784 + s] =
                (zred[0][t] + zred[1][t]) + (zred[2][t] + zred[3][t]);
    }
    int si = t >> 2, sub = t & 3;
    int s = s0 + si;
    if (s >= 784) return;
    int x = si & 7;
    int base0 = ((sub ^ (x >> 1)) << 4) | ((x & 1) << 3);
    int base1 = base0 ^ 8;
    uint4 v0 = *(const uint4*)&tile[si * 64 + base0];
    uint4 v1 = *(const uint4*)&tile[si * 64 + base1];
    size_t ro = (size_t)(b * 784 + s) * 384 + c0 + sub * 16;
    *(uint4*)(zf + ro)     = v0;
    *(uint4*)(zf + ro + 8) = v1;
}

// ---------------- distance GEMM + partial argmin: 128x128, dbuf, minimal 2-phase ----------------
// grid 3136 = 196 M-tiles x 16 N-chunks, 4 waves (2x2), LDS 2x(16K+16K) dbuf,
// 2 blocks/CU. Per K-step: issue next stage (gl_lds w=16) BEFORE reads+MFMA of
// current buffer; ONE __syncthreads (vmcnt0+lgkmcnt0+barrier) AFTER MFMA —
// stage latency hides under compute; prev barrier makes buffer overwrite safe.

#define STAGE4(gbase, lds) do { \
    _Pragma("unroll") for (int it_ = 0; it_ < 4; ++it_) { \
        uint32_t o_ = it_ * 4096u + (uint32_t)t * 16u; \
        uint32_t row_ = o_ >> 7, bo_ = o_ & 127u; \
        uint32_t so_ = row_ * 768u + (bo_ ^ ((row_ & 7u) << 4)); \
        gl_lds16((gbase) + so_, (lds) + o_); } } while (0)

__global__ __launch_bounds__(256, 2) void argmin4_kernel(
    const unsigned short* __restrict__ zf, const unsigned short* __restrict__ cb16,
    const float* __restrict__ cnorm, float2* __restrict__ partial) {
    __shared__ char Ab[2][16384];
    __shared__ char Bb[2][16384];
    __shared__ float2 comb[2][128];

    int t = threadIdx.x;
    int lane = t & 63, wave = t >> 6;
    int r = lane & 15, q = lane >> 4;
    int wm = wave >> 1, wn = wave & 1;

    // bijective XCD swizzle (nwg=3136, q=392): the 16 blocks sharing an
    // A-panel land on one XCD's L2.
    int raw = blockIdx.x;
    int lid = (raw & 7) * 392 + (raw >> 3);
    int mtile = lid >> 4;
    int nc = lid & 15;

    float cnr[4];
#pragma unroll
    for (int nt = 0; nt < 4; ++nt)
        cnr[nt] = cnorm[nc * 128 + wn * 64 + nt * 16 + r];

    const char* abase = (const char*)zf + (size_t)mtile * 98304;   // 128*768
    const char* bbase = (const char*)cb16 + (size_t)nc * 98304;

    f32x4 acc[4][4];
#pragma unroll
    for (int i = 0; i < 4; ++i)
#pragma unroll
        for (int j = 0; j < 4; ++j) acc[i][j] = (f32x4){0.f, 0.f, 0.f, 0.f};

    // prologue: stage K-step 0 into buf 0
    STAGE4(abase, Ab[0]);
    STAGE4(bbase, Bb[0]);
    __syncthreads();

#pragma unroll
    for (int ks = 0; ks < 6; ++ks) {
        const int cur = ks & 1;
        if (ks < 5) {   // prefetch next K-step into the other buffer
            STAGE4(abase + (ks + 1) * 128, Ab[cur ^ 1]);
            STAGE4(bbase + (ks + 1) * 128, Bb[cur ^ 1]);
        }
#pragma unroll
        for (int sub = 0; sub < 2; ++sub) {
            uint32_t kb = sub * 64u + (uint32_t)q * 16u;
            short8 a[4], b[4];
#pragma unroll
            for (int mt = 0; mt < 4; ++mt) {
                uint32_t row = (uint32_t)(wm * 64 + mt * 16 + r);
                a[mt] = *(const short8*)(Ab[cur] + row * 128u + (kb ^ ((row & 7u) << 4)));
            }
#pragma unroll
            for (int nt = 0; nt < 4; ++nt) {
                uint32_t row = (uint32_t)(wn * 64 + nt * 16 + r);
                b[nt] = *(const short8*)(Bb[cur] + row * 128u + (kb ^ ((row & 7u) << 4)));
            }
#pragma unroll
            for (int mt = 0; mt < 4; ++mt)
#pragma unroll
                for (int nt = 0; nt < 4; ++nt)
                    acc[mt][nt] = __builtin_amdgcn_mfma_f32_16x16x32_bf16(
                        a[mt], b[nt], acc[mt][nt], 0, 0, 0);
        }
        __syncthreads();   // drains this step's stage (landed under MFMA) + buffer-reuse fence
    }

    // score + argmin over this block's 128 cols.
    // C/D layout: col = lane&15 (r), row = q*4 + j.
    float minv[16];
    int   mini[16];
#pragma unroll
    for (int i = 0; i < 16; ++i) { minv[i] = 3.4e38f; mini[i] = 0; }
#pragma unroll
    for (int nt = 0; nt < 4; ++nt) {
        int col = nc * 128 + wn * 64 + nt * 16 + r;
        float cn = cnr[nt];
#pragma unroll
        for (int mt = 0; mt < 4; ++mt)
#pragma unroll
            for (int j = 0; j < 4; ++j) {
                float val = cn - 2.f * acc[mt][nt][j];
                int slot = mt * 4 + j;
                if (val < minv[slot]) { minv[slot] = val; mini[slot] = col; }
            }
    }
#pragma unroll
    for (int slot = 0; slot < 16; ++slot) {
        float v = minv[slot];
        int idx = mini[slot];
#pragma unroll
        for (int d = 1; d < 16; d <<= 1) {
            float ov = __shfl_xor(v, d);
            int   oi = __shfl_xor(idx, d);
            if (ov < v || (ov == v && oi < idx)) { v = ov; idx = oi; }
        }
        if (r == 0) {
            int mt = slot >> 2, j = slot & 3;
            float2 e; e.x = v; e.y = __int_as_float(idx);
            comb[wn][wm * 64 + mt * 16 + q * 4 + j] = e;
        }
    }
    __syncthreads();
    if (t < 128) {
        float2 c0 = comb[0][t], c1 = comb[1][t];
        float2 res = (c1.x < c0.x) ? c1 : c0;   // tie -> wn=0 (lower col)
        partial[(size_t)nc * M_TOK + mtile * 128 + t] = res;
    }
}

// ---------------- combine + gather + loss ----------------
__global__ __launch_bounds__(256) void gather_combine_kernel(
    const float* __restrict__ cb, const float2* __restrict__ partial,
    const float* __restrict__ znp, float* __restrict__ out) {
    __shared__ unsigned short tile[56 * 392];
    __shared__ int lidx[56];
    int t = threadIdx.x;
    int bid = blockIdx.x;                 // 448 = 32 b * 14 sT
    int b = bid / 14, sT = bid % 14;
    int n0 = b * 784 + sT * 56;
    float lt = 0.f;
    if (t < 56) {
        int n = n0 + t;
        float2 best = partial[n];
        int bi = __float_as_int(best.y);
#pragma unroll
        for (int ch = 1; ch < NC_CHUNKS; ++ch) {
            float2 p = partial[(size_t)ch * M_TOK + n];
            int pi = __float_as_int(p.y);
            if (p.x < best.x || (p.x == best.x && pi < bi)) { best = p; bi = pi; }
        }
        lidx[t] = bi;
        float zn = 0.f;
#pragma unroll
        for (int cT = 0; cT < 6; ++cT) zn += znp[cT * M_TOK + n];
        lt = best.x + zn;                 // ~ ||z_n - c_idx||^2
    }
    if (t < 64) {
#pragma unroll
        for (int d = 32; d; d >>= 1) lt += __shfl_xor(lt, d);
        if (t == 0) atomicAdd(out + OUT_ELEMS, lt * (1.25f / (float)OUT_ELEMS));
    }
    __syncthreads();
#pragma unroll
    for (int p = 0; p < 21; ++p) {
        int e = (p * 256 + t) * 4;
        int tok = e / 384;
        int c = e - tok * 384;
        int idx = lidx[tok];
        float4 v = *(const float4*)(cb + (size_t)idx * 384 + c);
        uint2 u;
        u.x = (uint32_t)f2bf(v.x) | ((uint32_t)f2bf(v.y) << 16);
        u.y = (uint32_t)f2bf(v.z) | ((uint32_t)f2bf(v.w) << 16);
        *(uint2*)&tile[tok * 392 + c] = u;
    }
    __syncthreads();
#pragma unroll
    for (int p = 0; p < 42; ++p) {
        int pp = p * 256 + t;
        int c = pp / 28;
        int j = (pp - c * 28) * 2;
        float f0 = bf2f(tile[j * 392 + c]);
        float f1 = bf2f(tile[(j + 1) * 392 + c]);
        size_t off = ((size_t)b * 384 + c) * 784 + (size_t)sT * 56 + j;
        float2 o; o.x = f0; o.y = f1;
        *(float2*)(out + off) = o;
    }
}

extern "C" void kernel_launch(void* const* d_in, const int* in_sizes, int n_in,
                              void* d_out, int out_size, void* d_ws, size_t ws_size,
                              hipStream_t stream) {
    const float* z  = (const float*)d_in[0];
    const float* cb = (const float*)d_in[1];
    float* out = (float*)d_out;
    char* ws = (char*)d_ws;

    // zf (token-major bf16 z, 19.3 MB) borrows d_out: fully consumed by
    // argmin4_kernel before gather_combine_kernel overwrites d_out.
    unsigned short* zf = (unsigned short*)d_out;

    unsigned short* cb16 = (unsigned short*)ws;            // 1,572,864 B
    float*  cnorm   = (float*)(ws + 1572864);              //     8,192 B
    float*  znp     = (float*)(ws + 1581056);              //   602,112 B
    float2* partial = (float2*)(ws + 2183168);             // 3,211,264 B

    hipMemsetAsync((void*)(out + OUT_ELEMS), 0, 4, stream);
    prep_transpose_kernel<<<3008, 256, 0, stream>>>(z, cb, zf, znp, cb16, cnorm);
    argmin4_kernel<<<3136, 256, 0, stream>>>(zf, cb16, cnorm, partial);
    gather_combine_kernel<<<448, 256, 0, stream>>>(cb, partial, znp, out);
}

// Round 5
// 98.813 us; speedup vs baseline: 1.3526x; 1.3268x over previous
//
#include <hip/hip_runtime.h>
#include <stdint.h>

// z (32,384,28,28) fp32; codebook (2048,384) fp32.
// N tokens = 25088, D = 384, K = 2048. out = z_q (9633792 f32) + loss (1 f32).
#define M_TOK 25088
#define D_DIM 384
#define K_CB  2048
#define OUT_ELEMS 9633792

typedef __attribute__((ext_vector_type(8))) short short8;
typedef __attribute__((ext_vector_type(4))) float f32x4;

static __device__ __forceinline__ unsigned short f2bf(float f) {
    uint32_t u = __float_as_uint(f);
    u += 0x7FFF + ((u >> 16) & 1);   // RNE
    return (unsigned short)(u >> 16);
}
static __device__ __forceinline__ float bf2f(unsigned short h) {
    return __uint_as_float(((uint32_t)h) << 16);
}
static __device__ __forceinline__ void gl_lds16(const void* g, void* l) {
    __builtin_amdgcn_global_load_lds((const __attribute__((address_space(1))) void*)g,
                                     (__attribute__((address_space(3))) void*)l,
                                     16, 0, 0);
}

// ---------------- fused: z transpose (+ ||z||^2 partials) and codebook prep ----------------
__global__ __launch_bounds__(256) void prep_transpose_kernel(
    const float* __restrict__ z, const float* __restrict__ cb,
    unsigned short* __restrict__ zf, float* __restrict__ znp,
    unsigned short* __restrict__ cb16, float* __restrict__ cnorm) {
    __shared__ unsigned short tile[64 * 64];
    __shared__ float zred[4][64];
    int bid = blockIdx.x;
    int t = threadIdx.x;
    if (bid >= 2496) {               // codebook prep: 512 blocks x 4 rows
        int lane = t & 63, wv = t >> 6;
        int row = (bid - 2496) * 4 + wv;
        const float* src = cb + (size_t)row * D_DIM;
        unsigned short* dst = cb16 + (size_t)row * D_DIM;
        float ss = 0.f;
#pragma unroll
        for (int i = 0; i < 6; ++i) {
            float v = src[lane + i * 64];
            dst[lane + i * 64] = f2bf(v);
            ss += v * v;
        }
#pragma unroll
        for (int d = 32; d; d >>= 1) ss += __shfl_xor(ss, d);
        if (lane == 0) cnorm[row] = ss;
        return;
    }
    // transpose path: (b,c,s) fp32 -> (token,c) bf16, 64x64 LDS tiles, XOR swizzle
    int sT = bid % 13;
    int rem = bid / 13;
    int cT = rem % 6;
    int b  = rem / 6;
    int c0 = cT * 64, s0 = sT * 64;
    int ls = t & 63;
    int wv = t >> 6;
    float ss = 0.f;
#pragma unroll
    for (int p = 0; p < 16; ++p) {
        int ci = p * 4 + wv;
        int s = s0 + ls;
        float v = 0.f;
        if (s < 784) v = z[(size_t)(b * 384 + c0 + ci) * 784 + s];
        ss += v * v;
        int cx = ci ^ ((ls & 7) << 3);
        tile[ls * 64 + cx] = f2bf(v);
    }
    zred[wv][ls] = ss;
    __syncthreads();
    if (t < 64) {
        int s = s0 + t;
        if (s < 784)
            znp[cT * M_TOK + b * 784 + s] =
                (zred[0][t] + zred[1][t]) + (zred[2][t] + zred[3][t]);
    }
    int si = t >> 2, sub = t & 3;
    int s = s0 + si;
    if (s >= 784) return;
    int x = si & 7;
    int base0 = ((sub ^ (x >> 1)) << 4) | ((x & 1) << 3);
    int base1 = base0 ^ 8;
    uint4 v0 = *(const uint4*)&tile[si * 64 + base0];
    uint4 v1 = *(const uint4*)&tile[si * 64 + base1];
    size_t ro = (size_t)(b * 784 + s) * 384 + c0 + sub * 16;
    *(uint4*)(zf + ro)     = v0;
    *(uint4*)(zf + ro + 8) = v1;
}

// ---------------- distance GEMM + FULL argmin: A-resident, B-streamed ----------------
// grid 196 (1 block = 1 M-tile of 128 tokens, ~1 block/CU). A-panel (96KB) + cnl
// (8KB) staged once; loop 16 nc x 6 ks = 96 steps, streaming B 16KB/step through
// a 3-slot ring, 2-deep prefetch, s_waitcnt vmcnt(4) + raw s_barrier (never 0
// mid-loop). Argmin kept as packed u32: (bits(1+score) & ~0x7FF) | col.
#define LDS_CNL 98304
#define LDS_B   106496
#define LDS_CMB 155648

#define WAIT4 do { asm volatile("s_waitcnt vmcnt(4)" ::: "memory"); \
    __builtin_amdgcn_s_barrier(); __builtin_amdgcn_sched_barrier(0); } while (0)
#define WAIT0 do { asm volatile("s_waitcnt vmcnt(0)" ::: "memory"); \
    __builtin_amdgcn_s_barrier(); __builtin_amdgcn_sched_barrier(0); } while (0)

__global__ __launch_bounds__(256) void argmin5_kernel(
    const unsigned short* __restrict__ zf, const unsigned short* __restrict__ cb16,
    const float* __restrict__ cnorm, int* __restrict__ midx, float* __restrict__ mdist) {
    extern __shared__ char smem[];
    char* As = smem;
    float* cnl = (float*)(smem + LDS_CNL);
    char* Bs = smem + LDS_B;                         // 3 slots x 16384
    uint32_t* comb = (uint32_t*)(smem + LDS_CMB);    // [2][128]

    int t = threadIdx.x;
    int lane = t & 63, wave = t >> 6;
    int r = lane & 15, q = lane >> 4;
    int wm = wave >> 1, wn = wave & 1;
    int blk = blockIdx.x;    // 196

    const char* abase = (const char*)zf + (size_t)blk * 98304;
    const char* bbase = (const char*)cb16;

    // per-thread staging geometry (loop-invariant)
    uint32_t swzT = ((uint32_t)((t >> 3) & 7)) << 4;
    uint32_t vb0  = (uint32_t)(t >> 3) * 768u + (((uint32_t)(t & 7) * 16u) ^ swzT);
    uint32_t dst0 = (uint32_t)t * 16u;

    // ---- prologue: stage A (24), cnl (2), B(0,0) (4), B(0,1) (4) ----
#pragma unroll
    for (int it = 0; it < 24; ++it) {
        uint32_t o   = it * 4096u + dst0;
        uint32_t row = o / 768u;
        uint32_t bo  = o - row * 768u;
        gl_lds16(abase + row * 768u + (bo ^ ((row & 7u) << 4)), As + o);
    }
#pragma unroll
    for (int it = 0; it < 2; ++it) {
        uint32_t o = it * 4096u + dst0;
        gl_lds16((const char*)cnorm + o, (char*)cnl + o);
    }
#pragma unroll
    for (int it = 0; it < 4; ++it)
        gl_lds16(bbase + vb0 + it * 24576, Bs + dst0 + it * 4096);          // (0,0)->slot0
#pragma unroll
    for (int it = 0; it < 4; ++it)
        gl_lds16(bbase + 128 + vb0 + it * 24576, Bs + 16384 + dst0 + it * 4096); // (0,1)->slot1

    // fragment read geometry (loop-invariant)
    uint32_t swz = ((uint32_t)(r & 7)) << 4;
    uint32_t kq0 = ((uint32_t)q * 16u) ^ swz;
    uint32_t kq1 = (64u + (uint32_t)q * 16u) ^ swz;
    uint32_t rba = (uint32_t)(wm * 64 + r) * 768u;
    uint32_t rbb = (uint32_t)(wn * 64 + r) * 128u;

    uint32_t pmin[16];
#pragma unroll
    for (int i = 0; i < 16; ++i) pmin[i] = 0xFFFFFFFFu;
    f32x4 acc[4][4];
    const f32x4 zero4 = {0.f, 0.f, 0.f, 0.f};

    WAIT4;   // A + cnl + B(0,0) complete; B(0,1)'s 4 still in flight

#pragma unroll 1
    for (int nc = 0; nc < 16; ++nc) {
#pragma unroll
        for (int ks = 0; ks < 6; ++ks) {
            // stage step+2 into slot (ks+2)%3
            if (!(nc == 15 && ks >= 4)) {
                const int s_ks = (ks + 2) % 6;       // compile-time
                const int slot = (ks + 2) % 3;       // compile-time
                int s_nc = (ks >= 4) ? nc + 1 : nc;
                const char* bB = bbase + (size_t)s_nc * 98304 + s_ks * 128;
#pragma unroll
                for (int it = 0; it < 4; ++it)
                    gl_lds16(bB + vb0 + it * 24576,
                             Bs + slot * 16384 + dst0 + it * 4096);
            }
            const int cur = ks % 3;                  // compile-time
#pragma unroll
            for (int sub = 0; sub < 2; ++sub) {
                uint32_t kq = sub ? kq1 : kq0;
                uint32_t ca = rba + (uint32_t)(ks * 128) + kq;
                uint32_t cb_ = rbb + kq + (uint32_t)(cur * 16384);
                short8 a[4], b[4];
#pragma unroll
                for (int mt = 0; mt < 4; ++mt)
                    a[mt] = *(const short8*)(As + ca + mt * 12288);
#pragma unroll
                for (int nt = 0; nt < 4; ++nt)
                    b[nt] = *(const short8*)(Bs + cb_ + nt * 2048);
#pragma unroll
                for (int mt = 0; mt < 4; ++mt)
#pragma unroll
                    for (int nt = 0; nt < 4; ++nt)
                        acc[mt][nt] = __builtin_amdgcn_mfma_f32_16x16x32_bf16(
                            a[mt], b[nt],
                            (ks == 0 && sub == 0) ? zero4 : acc[mt][nt], 0, 0, 0);
            }
            if (ks == 5) {   // score + packed running argmin for this nc
#pragma unroll
                for (int nt = 0; nt < 4; ++nt) {
                    float cn1 = 1.0f + cnl[nc * 128 + wn * 64 + nt * 16 + r];
                    uint32_t col = (uint32_t)(nc * 128 + wn * 64 + nt * 16 + r);
#pragma unroll
                    for (int mt = 0; mt < 4; ++mt)
#pragma unroll
                        for (int j = 0; j < 4; ++j) {
                            float s1 = fmaf(acc[mt][nt][j], -2.0f, cn1);
                            uint32_t u = (__float_as_uint(s1) & 0xFFFFF800u) | col;
                            int sl = mt * 4 + j;
                            pmin[sl] = u < pmin[sl] ? u : pmin[sl];
                        }
                }
            }
            if (!(nc == 15 && ks == 5)) {
                if (nc == 15 && ks == 4) { WAIT0; } else { WAIT4; }
            }
        }
    }

    // final 16-lane reduce per slot; cross-wn via LDS
#pragma unroll
    for (int sl = 0; sl < 16; ++sl) {
        uint32_t v = pmin[sl];
#pragma unroll
        for (int d = 1; d < 16; d <<= 1) {
            uint32_t ov = __shfl_xor(v, d);
            v = ov < v ? ov : v;
        }
        if (r == 0) {
            int mt = sl >> 2, j = sl & 3;
            comb[wn * 128 + wm * 64 + mt * 16 + q * 4 + j] = v;
        }
    }
    __syncthreads();
    if (t < 128) {
        uint32_t m0 = comb[t], m1 = comb[128 + t];
        uint32_t m = m1 < m0 ? m1 : m0;
        int n = blk * 128 + t;
        midx[n]  = (int)(m & 0x7FFu);
        mdist[n] = __uint_as_float(m & 0xFFFFF800u) - 1.0f;
    }
}

// ---------------- gather + output + loss ----------------
__global__ __launch_bounds__(256) void gather_combine_kernel(
    const float* __restrict__ cb, const int* __restrict__ midx,
    const float* __restrict__ mdist, const float* __restrict__ znp,
    float* __restrict__ out) {
    __shared__ unsigned short tile[56 * 392];
    __shared__ int lidx[56];
    int t = threadIdx.x;
    int bid = blockIdx.x;                 // 448 = 32 b * 14 sT
    int b = bid / 14, sT = bid % 14;
    int n0 = b * 784 + sT * 56;
    float lt = 0.f;
    if (t < 56) {
        int n = n0 + t;
        int bi = midx[n];
        lidx[t] = bi;
        float zn = 0.f;
#pragma unroll
        for (int cT = 0; cT < 6; ++cT) zn += znp[cT * M_TOK + n];
        lt = mdist[n] + zn;               // ~ ||z_n - c_idx||^2
    }
    if (t < 64) {
#pragma unroll
        for (int d = 32; d; d >>= 1) lt += __shfl_xor(lt, d);
        if (t == 0) atomicAdd(out + OUT_ELEMS, lt * (1.25f / (float)OUT_ELEMS));
    }
    __syncthreads();
#pragma unroll
    for (int p = 0; p < 21; ++p) {
        int e = (p * 256 + t) * 4;
        int tok = e / 384;
        int c = e - tok * 384;
        int idx = lidx[tok];
        float4 v = *(const float4*)(cb + (size_t)idx * 384 + c);
        uint2 u;
        u.x = (uint32_t)f2bf(v.x) | ((uint32_t)f2bf(v.y) << 16);
        u.y = (uint32_t)f2bf(v.z) | ((uint32_t)f2bf(v.w) << 16);
        *(uint2*)&tile[tok * 392 + c] = u;
    }
    __syncthreads();
#pragma unroll
    for (int p = 0; p < 42; ++p) {
        int pp = p * 256 + t;
        int c = pp / 28;
        int j = (pp - c * 28) * 2;
        float f0 = bf2f(tile[j * 392 + c]);
        float f1 = bf2f(tile[(j + 1) * 392 + c]);
        size_t off = ((size_t)b * 384 + c) * 784 + (size_t)sT * 56 + j;
        float2 o; o.x = f0; o.y = f1;
        *(float2*)(out + off) = o;
    }
}

extern "C" void kernel_launch(void* const* d_in, const int* in_sizes, int n_in,
                              void* d_out, int out_size, void* d_ws, size_t ws_size,
                              hipStream_t stream) {
    const float* z  = (const float*)d_in[0];
    const float* cb = (const float*)d_in[1];
    float* out = (float*)d_out;
    char* ws = (char*)d_ws;

    // zf (token-major bf16 z, 19.3 MB) borrows d_out: fully consumed by
    // argmin5_kernel (prologue A-stage) before gather_combine overwrites d_out.
    unsigned short* zf = (unsigned short*)d_out;

    unsigned short* cb16 = (unsigned short*)ws;            // 1,572,864 B
    float*  cnorm   = (float*)(ws + 1572864);              //     8,192 B
    float*  znp     = (float*)(ws + 1581056);              //   602,112 B
    int*    midx    = (int*)(ws + 2183168);                //   100,352 B
    float*  mdist   = (float*)(ws + 2283520);              //   100,352 B

    hipMemsetAsync((void*)(out + OUT_ELEMS), 0, 4, stream);
    hipFuncSetAttribute((const void*)argmin5_kernel,
                        hipFuncAttributeMaxDynamicSharedMemorySize, 156672);
    prep_transpose_kernel<<<3008, 256, 0, stream>>>(z, cb, zf, znp, cb16, cnorm);
    argmin5_kernel<<<196, 256, 156672, stream>>>(zf, cb16, cnorm, midx, mdist);
    gather_combine_kernel<<<448, 256, 0, stream>>>(cb, midx, mdist, znp, out);
}

// Round 6
// 91.174 us; speedup vs baseline: 1.4659x; 1.0838x over previous
//
#include <hip/hip_runtime.h>
#include <stdint.h>

// z (32,384,28,28) fp32; codebook (2048,384) fp32.
// N tokens = 25088, D = 384, K = 2048. out = z_q (9633792 f32) + loss (1 f32).
#define M_TOK 25088
#define D_DIM 384
#define K_CB  2048
#define OUT_ELEMS 9633792

typedef __attribute__((ext_vector_type(8))) short short8;
typedef __attribute__((ext_vector_type(4))) float f32x4;

static __device__ __forceinline__ unsigned short f2bf(float f) {
    uint32_t u = __float_as_uint(f);
    u += 0x7FFF + ((u >> 16) & 1);   // RNE
    return (unsigned short)(u >> 16);
}
static __device__ __forceinline__ float bf2f(unsigned short h) {
    return __uint_as_float(((uint32_t)h) << 16);
}
static __device__ __forceinline__ void gl_lds16(const void* g, void* l) {
    __builtin_amdgcn_global_load_lds((const __attribute__((address_space(1))) void*)g,
                                     (__attribute__((address_space(3))) void*)l,
                                     16, 0, 0);
}

// ---------------- fused: z transpose (+ ||z||^2 partials) and codebook prep ----------------
__global__ __launch_bounds__(256) void prep_transpose_kernel(
    const float* __restrict__ z, const float* __restrict__ cb,
    unsigned short* __restrict__ zf, float* __restrict__ znp,
    unsigned short* __restrict__ cb16, float* __restrict__ cnorm) {
    __shared__ unsigned short tile[64 * 64];
    __shared__ float zred[4][64];
    int bid = blockIdx.x;
    int t = threadIdx.x;
    if (bid >= 2496) {               // codebook prep: 512 blocks x 4 rows
        int lane = t & 63, wv = t >> 6;
        int row = (bid - 2496) * 4 + wv;
        const float* src = cb + (size_t)row * D_DIM;
        unsigned short* dst = cb16 + (size_t)row * D_DIM;
        float ss = 0.f;
#pragma unroll
        for (int i = 0; i < 6; ++i) {
            float v = src[lane + i * 64];
            dst[lane + i * 64] = f2bf(v);
            ss += v * v;
        }
#pragma unroll
        for (int d = 32; d; d >>= 1) ss += __shfl_xor(ss, d);
        if (lane == 0) cnorm[row] = ss;
        return;
    }
    // transpose path: (b,c,s) fp32 -> (token,c) bf16, 64x64 LDS tiles, XOR swizzle
    int sT = bid % 13;
    int rem = bid / 13;
    int cT = rem % 6;
    int b  = rem / 6;
    int c0 = cT * 64, s0 = sT * 64;
    int ls = t & 63;
    int wv = t >> 6;
    float ss = 0.f;
#pragma unroll
    for (int p = 0; p < 16; ++p) {
        int ci = p * 4 + wv;
        int s = s0 + ls;
        float v = 0.f;
        if (s < 784) v = z[(size_t)(b * 384 + c0 + ci) * 784 + s];
        ss += v * v;
        int cx = ci ^ ((ls & 7) << 3);
        tile[ls * 64 + cx] = f2bf(v);
    }
    zred[wv][ls] = ss;
    __syncthreads();
    if (t < 64) {
        int s = s0 + t;
        if (s < 784)
            znp[cT * M_TOK + b * 784 + s] =
                (zred[0][t] + zred[1][t]) + (zred[2][t] + zred[3][t]);
    }
    int si = t >> 2, sub = t & 3;
    int s = s0 + si;
    if (s >= 784) return;
    int x = si & 7;
    int base0 = ((sub ^ (x >> 1)) << 4) | ((x & 1) << 3);
    int base1 = base0 ^ 8;
    uint4 v0 = *(const uint4*)&tile[si * 64 + base0];
    uint4 v1 = *(const uint4*)&tile[si * 64 + base1];
    size_t ro = (size_t)(b * 784 + s) * 384 + c0 + sub * 16;
    *(uint4*)(zf + ro)     = v0;
    *(uint4*)(zf + ro + 8) = v1;
}

// ---------------- distance GEMM + FULL argmin: A-resident, 8 waves, 4-slot ring ----------------
// grid 196 (1 block = 128 tokens), 512 threads = 8 waves (2 wm x 4 wn), wave
// tile 64x32. LDS: A 96K + B-ring 4x16K = 160K exactly. 96 steps (16 nc x 6 ks);
// per step stage 16KB (2 gl_lds/thread) at distance 3; steady-state vmcnt(4),
// tail 2,0. 2 waves/SIMD give cross-wave latency hiding (m114 mechanism).

#define WAITN(N) do { asm volatile("s_waitcnt vmcnt(" #N ")" ::: "memory"); \
    __builtin_amdgcn_s_barrier(); __builtin_amdgcn_sched_barrier(0); } while (0)

#define STB(CHOFF, SLOT) do { \
    gl_lds16(bst + (CHOFF), ring + (SLOT) * 16384 + t16); \
    gl_lds16(bst + (CHOFF) + 49152, ring + (SLOT) * 16384 + 8192 + t16); } while (0)

#define CSTEP(CUR, KSOFF, FIRST) do { \
    const char* Bp_ = ring + (CUR) * 16384 + rbb; \
    _Pragma("unroll") \
    for (int sub = 0; sub < 2; ++sub) { \
        uint32_t kq = sub ? kq1 : kq0; \
        short8 a[4], b[2]; \
        _Pragma("unroll") for (int mt = 0; mt < 4; ++mt) \
            a[mt] = *(const short8*)(Arow + mt * 12288 + (KSOFF) + kq); \
        _Pragma("unroll") for (int nt = 0; nt < 2; ++nt) \
            b[nt] = *(const short8*)(Bp_ + nt * 2048 + kq); \
        _Pragma("unroll") for (int mt = 0; mt < 4; ++mt) \
        _Pragma("unroll") for (int nt = 0; nt < 2; ++nt) \
            acc[mt][nt] = __builtin_amdgcn_mfma_f32_16x16x32_bf16( \
                a[mt], b[nt], ((FIRST) && sub == 0) ? zero4 : acc[mt][nt], 0, 0, 0); \
    } } while (0)

#define SCORE(NCOL) do { \
    _Pragma("unroll") for (int nt = 0; nt < 2; ++nt) { \
        int col = (NCOL) + wn * 32 + nt * 16 + r; \
        float cn1 = 1.0f + cnorm[col]; \
        _Pragma("unroll") for (int mt = 0; mt < 4; ++mt) \
        _Pragma("unroll") for (int j = 0; j < 4; ++j) { \
            float s1 = fmaf(acc[mt][nt][j], -2.0f, cn1); \
            uint32_t u = (__float_as_uint(s1) & 0xFFFFF800u) | (uint32_t)col; \
            int sl = mt * 4 + j; \
            pmin[sl] = u < pmin[sl] ? u : pmin[sl]; \
        } } } while (0)

// e=0 steps ks 0..5 of an (even nc, odd nc) pair: cur = ks&3, stage slot (ks+3)&3
#define E0_STEPS(NCOL) \
    STB(384, 3);    CSTEP(0, 0, true);    WAITN(4); \
    STB(512, 0);    CSTEP(1, 128, false); WAITN(4); \
    STB(640, 1);    CSTEP(2, 256, false); WAITN(4); \
    STB(98304, 2);  CSTEP(3, 384, false); WAITN(4); \
    STB(98432, 3);  CSTEP(0, 512, false); WAITN(4); \
    STB(98560, 0);  CSTEP(1, 640, false); SCORE(NCOL); WAITN(4);
// e=1: cur = (ks+2)&3, stage slot (ks+1)&3
#define E1_HEAD \
    STB(98688, 1);  CSTEP(2, 0, true);    WAITN(4); \
    STB(98816, 2);  CSTEP(3, 128, false); WAITN(4); \
    STB(98944, 3);  CSTEP(0, 256, false); WAITN(4);
#define E1_TAIL_FULL(NCOL) \
    STB(196608, 0); CSTEP(1, 384, false); WAITN(4); \
    STB(196736, 1); CSTEP(2, 512, false); WAITN(4); \
    STB(196864, 2); CSTEP(3, 640, false); SCORE((NCOL) + 128); WAITN(4);
#define E1_TAIL_LAST(NCOL) \
    CSTEP(1, 384, false); WAITN(2); \
    CSTEP(2, 512, false); WAITN(0); \
    CSTEP(3, 640, false); SCORE((NCOL) + 128);

__global__ __launch_bounds__(512, 2) void argmin6_kernel(
    const unsigned short* __restrict__ zf, const unsigned short* __restrict__ cb16,
    const float* __restrict__ cnorm, int* __restrict__ midx, float* __restrict__ mdist) {
    extern __shared__ char smem[];
    char* As = smem;                 // 96 KB A panel (128 tok x 384 k, swizzled)
    char* ring = smem + 98304;       // 4 x 16 KB B slots

    int t = threadIdx.x;
    int lane = t & 63, wave = t >> 6;
    int r = lane & 15, q = lane >> 4;
    int wm = wave >> 2, wn = wave & 3;
    int blk = blockIdx.x;            // 196

    const char* abase = (const char*)zf + (size_t)blk * 98304;
    const char* bbase = (const char*)cb16;

    uint32_t t16 = (uint32_t)t * 16u;
    uint32_t brow = (uint32_t)t >> 3;     // 0..63
    uint32_t vb0 = brow * 768u + ((((uint32_t)t & 7u) * 16u) ^ ((brow & 7u) << 4));

    // ---- prologue: A (12 rounds of 8KB), then B chunks 0,1,2 -> slots 0,1,2
#pragma unroll
    for (int it = 0; it < 12; ++it) {
        uint32_t o = it * 8192u + t16;
        uint32_t row = o / 768u;
        uint32_t bo = o - row * 768u;
        gl_lds16(abase + row * 768u + (bo ^ ((row & 7u) << 4)), As + o);
    }
    {
        const char* bst = bbase + vb0;
#pragma unroll
        for (int s = 0; s < 3; ++s) {
            gl_lds16(bst + s * 128, ring + s * 16384 + t16);
            gl_lds16(bst + s * 128 + 49152, ring + s * 16384 + 8192 + t16);
        }
    }

    // fragment read geometry (loop-invariant)
    uint32_t swz = ((uint32_t)(r & 7)) << 4;
    uint32_t kq0 = ((uint32_t)q * 16u) ^ swz;
    uint32_t kq1 = (64u + (uint32_t)q * 16u) ^ swz;
    const char* Arow = As + (uint32_t)(wm * 64 + r) * 768u;
    uint32_t rbb = (uint32_t)(wn * 32 + r) * 128u;

    uint32_t pmin[16];
#pragma unroll
    for (int i = 0; i < 16; ++i) pmin[i] = 0xFFFFFFFFu;
    f32x4 acc[4][2];
    const f32x4 zero4 = {0.f, 0.f, 0.f, 0.f};

    WAITN(4);   // A + B(0) complete; B(1),B(2) in flight

    int ncol = 0;
    const char* bstp = bbase + vb0;
#pragma unroll 1
    for (int ncp = 0; ncp < 7; ++ncp) {
        const char* bst = bstp;
        E0_STEPS(ncol);
        E1_HEAD;
        E1_TAIL_FULL(ncol);
        bstp += 196608;
        ncol += 256;
    }
    {   // pair 7: nc=14 full, nc=15 tail (stages for steps 93..95 only)
        const char* bst = bstp;
        E0_STEPS(ncol);
        E1_HEAD;
        E1_TAIL_LAST(ncol);
    }

    // ---- final reduce: 16-lane shfl per row-slot, cross-wn via LDS (A region reusable)
    __syncthreads();
    uint32_t* comb = (uint32_t*)smem;    // [4 wn][128 rows]
#pragma unroll
    for (int sl = 0; sl < 16; ++sl) {
        uint32_t v = pmin[sl];
#pragma unroll
        for (int d = 1; d < 16; d <<= 1) {
            uint32_t ov = __shfl_xor(v, d);
            v = ov < v ? ov : v;
        }
        if (r == 0) {
            int row = wm * 64 + (sl >> 2) * 16 + q * 4 + (sl & 3);
            comb[wn * 128 + row] = v;
        }
    }
    __syncthreads();
    if (t < 128) {
        uint32_t m0 = comb[t];
        uint32_t m1 = comb[128 + t];
        uint32_t m2 = comb[256 + t];
        uint32_t m3 = comb[384 + t];
        uint32_t ma = m1 < m0 ? m1 : m0;
        uint32_t mb = m3 < m2 ? m3 : m2;
        uint32_t m = mb < ma ? mb : ma;
        int n = blk * 128 + t;
        midx[n]  = (int)(m & 0x7FFu);
        mdist[n] = __uint_as_float(m & 0xFFFFF800u) - 1.0f;
    }
}

// ---------------- gather + output + loss ----------------
__global__ __launch_bounds__(256) void gather_combine_kernel(
    const float* __restrict__ cb, const int* __restrict__ midx,
    const float* __restrict__ mdist, const float* __restrict__ znp,
    float* __restrict__ out) {
    __shared__ unsigned short tile[56 * 392];
    __shared__ int lidx[56];
    int t = threadIdx.x;
    int bid = blockIdx.x;                 // 448 = 32 b * 14 sT
    int b = bid / 14, sT = bid % 14;
    int n0 = b * 784 + sT * 56;
    float lt = 0.f;
    if (t < 56) {
        int n = n0 + t;
        lidx[t] = midx[n];
        float zn = 0.f;
#pragma unroll
        for (int cT = 0; cT < 6; ++cT) zn += znp[cT * M_TOK + n];
        lt = mdist[n] + zn;               // ~ ||z_n - c_idx||^2
    }
    if (t < 64) {
#pragma unroll
        for (int d = 32; d; d >>= 1) lt += __shfl_xor(lt, d);
        if (t == 0) atomicAdd(out + OUT_ELEMS, lt * (1.25f / (float)OUT_ELEMS));
    }
    __syncthreads();
#pragma unroll
    for (int p = 0; p < 21; ++p) {
        int e = (p * 256 + t) * 4;
        int tok = e / 384;
        int c = e - tok * 384;
        int idx = lidx[tok];
        float4 v = *(const float4*)(cb + (size_t)idx * 384 + c);
        uint2 u;
        u.x = (uint32_t)f2bf(v.x) | ((uint32_t)f2bf(v.y) << 16);
        u.y = (uint32_t)f2bf(v.z) | ((uint32_t)f2bf(v.w) << 16);
        *(uint2*)&tile[tok * 392 + c] = u;
    }
    __syncthreads();
#pragma unroll
    for (int p = 0; p < 42; ++p) {
        int pp = p * 256 + t;
        int c = pp / 28;
        int j = (pp - c * 28) * 2;
        float f0 = bf2f(tile[j * 392 + c]);
        float f1 = bf2f(tile[(j + 1) * 392 + c]);
        size_t off = ((size_t)b * 384 + c) * 784 + (size_t)sT * 56 + j;
        float2 o; o.x = f0; o.y = f1;
        *(float2*)(out + off) = o;
    }
}

extern "C" void kernel_launch(void* const* d_in, const int* in_sizes, int n_in,
                              void* d_out, int out_size, void* d_ws, size_t ws_size,
                              hipStream_t stream) {
    const float* z  = (const float*)d_in[0];
    const float* cb = (const float*)d_in[1];
    float* out = (float*)d_out;
    char* ws = (char*)d_ws;

    // zf (token-major bf16 z, 19.3 MB) borrows d_out: fully consumed by
    // argmin6_kernel (prologue A-stage) before gather_combine overwrites d_out.
    unsigned short* zf = (unsigned short*)d_out;

    unsigned short* cb16 = (unsigned short*)ws;            // 1,572,864 B
    float*  cnorm   = (float*)(ws + 1572864);              //     8,192 B
    float*  znp     = (float*)(ws + 1581056);              //   602,112 B
    int*    midx    = (int*)(ws + 2183168);                //   100,352 B
    float*  mdist   = (float*)(ws + 2283520);              //   100,352 B

    hipMemsetAsync((void*)(out + OUT_ELEMS), 0, 4, stream);
    hipFuncSetAttribute((const void*)argmin6_kernel,
                        hipFuncAttributeMaxDynamicSharedMemorySize, 163840);
    prep_transpose_kernel<<<3008, 256, 0, stream>>>(z, cb, zf, znp, cb16, cnorm);
    argmin6_kernel<<<196, 512, 163840, stream>>>(zf, cb16, cnorm, midx, mdist);
    gather_combine_kernel<<<448, 256, 0, stream>>>(cb, midx, mdist, znp, out);
}